// Round 24
// baseline (237.549 us; speedup 1.0000x reference)
//
#include <hip/hip_runtime.h>

// Chamfer forward: dist0[i] = min_j ||pc0[i]-pc1[j]||^2 ; out = mean(dist0[dist0<=2])
// N = M = 65536 i.i.d. N(0,1)^3 points, fp32.
// Fine grid G=64 (h=0.125), counting sort, THREE-phase query. Structure = R23
// with TWO constants changed:
//  - deep_kernel candidate loop unroll 4 -> 16. R23's deep (60us, occ 5%) was
//    ILP-starved: 64 serial batches x ~900cyc L3/HBM latency = 24us/block.
//    16 loads in flight -> 16 batches -> ~6us/block.
//  - DBLOCKS 512 -> 2048: all deep queries in one parallel round.
// Phase 2 (pending) keeps rings 1..2 only (R23 verified: off the top-5).

constexpr int   NPTS  = 65536;
constexpr int   G     = 64;
constexpr int   NC    = G * G * G;    // 262144 fine cells
constexpr float H     = 0.125f;
constexpr float ORG   = -4.0f;
constexpr float INVH  = 8.0f;
constexpr int   G3    = 32;           // medium geometry (phase 2 rings)
constexpr float H3    = 0.25f;
constexpr float INVH3 = 4.0f;
constexpr int   BLOCK = 256;
constexpr int   PBLOCKS = 1024;       // pending grid (wave per query)
constexpr int   DBLOCKS = 2048;       // deep grid (block per query; done-counter)
constexpr int   SB    = 128;          // scan blocks per fine array
constexpr int   CHUNK = NC / SB;      // 2048 counts per scan block (2/thread)

__device__ __forceinline__ int cellOf(float x) {
  int c = (int)floorf((x - ORG) * INVH);
  return min(max(c, 0), G - 1);
}
__device__ __forceinline__ int cellOf3(float x) {
  int c = (int)floorf((x - ORG) * INVH3);
  return min(max(c, 0), G3 - 1);
}

__global__ __launch_bounds__(BLOCK) void count_kernel(
    const float* __restrict__ pc0, const float* __restrict__ pc1,
    unsigned* __restrict__ counts0, unsigned* __restrict__ counts1) {
  const int gid = blockIdx.x * BLOCK + threadIdx.x;
  const float* p; unsigned* cnt; int i;
  if (gid < NPTS) { p = pc1; cnt = counts1; i = gid; }
  else            { p = pc0; cnt = counts0; i = gid - NPTS; }
  const float x = p[3 * i], y = p[3 * i + 1], z = p[3 * i + 2];
  atomicAdd(&cnt[(cellOf(z) * G + cellOf(y)) * G + cellOf(x)], 1u);
}

// Phase A: per-block partial sums. grid=(SB,2); y=0->counts1, y=1->counts0.
__global__ __launch_bounds__(1024) void scan_partial_kernel(
    const unsigned* __restrict__ counts0, const unsigned* __restrict__ counts1,
    unsigned* __restrict__ partials) {
  const unsigned* counts = blockIdx.y ? counts0 : counts1;
  const int base = blockIdx.x * CHUNK + threadIdx.x * 2;
  unsigned sum = counts[base] + counts[base + 1];
  for (int o = 32; o; o >>= 1) sum += __shfl_down(sum, o, 64);
  __shared__ unsigned ws[16];
  if ((threadIdx.x & 63) == 0) ws[threadIdx.x >> 6] = sum;
  __syncthreads();
  if (threadIdx.x == 0) {
    unsigned t = 0;
    for (int w = 0; w < 16; ++w) t += ws[w];
    partials[blockIdx.y * SB + blockIdx.x] = t;
  }
}

// Phase B: one 256-thread block exclusively scans both 128-entry partial arrays.
__global__ __launch_bounds__(256) void scan_mid_kernel(
    unsigned* __restrict__ partials) {
  const int tid = threadIdx.x;
  const int g   = tid >> 7;
  const int li  = tid & 127;
  const unsigned v = partials[g * SB + li];
  unsigned inc = v;
  for (int o = 1; o < 64; o <<= 1) {
    const unsigned t = __shfl_up(inc, o, 64);
    if ((tid & 63) >= o) inc += t;
  }
  __shared__ unsigned wt[4];
  if ((tid & 63) == 63) wt[tid >> 6] = inc;
  __syncthreads();
  const unsigned woff = ((tid >> 6) & 1) ? wt[g << 1] : 0u;
  partials[g * SB + li] = woff + inc - v;
}

// Phase C: block scan + offset -> cur (CSR starts). grid=(SB,2).
__global__ __launch_bounds__(1024) void scan_final_kernel(
    const unsigned* __restrict__ counts0, unsigned* __restrict__ cur0,
    const unsigned* __restrict__ counts1, unsigned* __restrict__ cur1,
    const unsigned* __restrict__ partials) {
  const unsigned* counts = blockIdx.y ? counts0 : counts1;
  unsigned* cur          = blockIdx.y ? cur0    : cur1;
  const int tid = threadIdx.x;
  const int base = blockIdx.x * CHUNK + tid * 2;
  const unsigned a = counts[base], b = counts[base + 1];
  const unsigned tsum = a + b;
  unsigned inc = tsum;
  for (int o = 1; o < 64; o <<= 1) {
    const unsigned t = __shfl_up(inc, o, 64);
    if ((tid & 63) >= o) inc += t;
  }
  __shared__ unsigned wt[16];
  if ((tid & 63) == 63) wt[tid >> 6] = inc;
  __syncthreads();
  if (tid < 16) {
    unsigned w = wt[tid];
    for (int o = 1; o < 16; o <<= 1) {
      const unsigned t = __shfl_up(w, o, 16);
      if (tid >= o) w += t;
    }
    wt[tid] = w;
  }
  __syncthreads();
  const unsigned woff = (tid >> 6) ? wt[(tid >> 6) - 1] : 0u;
  const unsigned off =
      partials[blockIdx.y * SB + blockIdx.x] + woff + inc - tsum;
  cur[base] = off;
  cur[base + 1] = off + a;
}

// After scatter, cur[c] = CSR inclusive end of cell c (start = cur[c-1]).
__global__ __launch_bounds__(BLOCK) void scatter_kernel(
    const float* __restrict__ pc0, const float* __restrict__ pc1,
    unsigned* __restrict__ cur0, unsigned* __restrict__ cur1,
    float4* __restrict__ q, float4* __restrict__ s) {
  const int gid = blockIdx.x * BLOCK + threadIdx.x;
  const float* p; unsigned* cur; float4* dst; int i;
  if (gid < NPTS) { p = pc1; cur = cur1; dst = s; i = gid; }
  else            { p = pc0; cur = cur0; dst = q; i = gid - NPTS; }
  const float x = p[3 * i], y = p[3 * i + 1], z = p[3 * i + 2];
  const int cid = (cellOf(z) * G + cellOf(y)) * G + cellOf(x);
  dst[atomicAdd(&cur[cid], 1u)] = make_float4(x, y, z, 0.f);
}

// Phase 1: fine rings 0..1, 2 lanes per query; push unfinished to worklist.
__global__ __launch_bounds__(BLOCK) void query_kernel(
    const float4* __restrict__ q, const unsigned* __restrict__ ends,
    const float4* __restrict__ s,
    unsigned* __restrict__ wl, float* __restrict__ wlBest,
    unsigned* __restrict__ pendCnt, float* __restrict__ bkt) {
  const int gtid = blockIdx.x * BLOCK + threadIdx.x;
  const int i   = gtid >> 1;        // query index
  const int sub = gtid & 1;         // sub-lane
  const float4 p = q[i];
  const int cx = cellOf(p.x), cy = cellOf(p.y), cz = cellOf(p.z);
  const int x0 = max(cx - 1, 0), x1 = min(cx + 1, G - 1);

  unsigned rs[9], re[9];
#pragma unroll
  for (int rr = 0; rr < 9; ++rr) {
    const int zz = cz + rr / 3 - 1, yy = cy + rr % 3 - 1;
    const bool ok = (zz >= 0) && (zz < G) && (yy >= 0) && (yy < G);
    const int rb = ok ? (zz * G + yy) * G : 0;
    rs[rr] = ok ? ((rb + x0) ? ends[rb + x0 - 1] : 0u) : 0u;
    re[rr] = ok ? ends[rb + x1] : 0u;
  }
  float best = 3.4e38f;
#pragma unroll
  for (int rr = 0; rr < 9; ++rr) {
#pragma unroll 4
    for (unsigned j = rs[rr] + sub; j < re[rr]; j += 2) {
      const float4 c = s[j];
      const float dx = p.x - c.x, dy = p.y - c.y, dz = p.z - c.z;
      best = fminf(best, fmaf(dx, dx, fmaf(dy, dy, dz * dz)));
    }
  }
  best = fminf(best, __shfl_xor(best, 1, 64));   // combine the 2 sub-lanes

  float v = 0.f, c = 0.f;
  if (sub == 0) {
    if (best > H * H) {            // not provably exact -> phase 2
      const unsigned k = atomicAdd(pendCnt, 1u);
      wl[k] = (unsigned)i; wlBest[k] = best;
    } else if (best <= 2.0f) { v = best; c = 1.0f; }
  }

  for (int o = 32; o; o >>= 1) {
    v += __shfl_down(v, o, 64);
    c += __shfl_down(c, o, 64);
  }
  __shared__ float wsum[BLOCK / 64], wcnt[BLOCK / 64];
  const int wid = threadIdx.x >> 6;
  if ((threadIdx.x & 63) == 0) { wsum[wid] = v; wcnt[wid] = c; }
  __syncthreads();
  if (threadIdx.x == 0) {
    float bv = 0.f, bc = 0.f;
    for (int w = 0; w < BLOCK / 64; ++w) { bv += wsum[w]; bc += wcnt[w]; }
    if (bc != 0.f) {
      atomicAdd(&bkt[2 * (blockIdx.x & 63) + 0], bv);
      atomicAdd(&bkt[2 * (blockIdx.x & 63) + 1], bc);
    }
  }
}

// Phase 2: wave per pending query; MEDIUM rings 1..2 only over the FINE CSR
// (one medium row = 4 fine rows). Exact if best <= 0.25 (unsearched >= 0.5).
// Survivors (far-tail) go to the deep worklist.
__global__ __launch_bounds__(BLOCK) void pending_kernel(
    const float4* __restrict__ q,
    const unsigned* __restrict__ ends, const float4* __restrict__ s,
    const unsigned* __restrict__ wl, const float* __restrict__ wlBest,
    unsigned* __restrict__ pendCnt, float* __restrict__ bkt,
    unsigned* __restrict__ wl2, unsigned* __restrict__ deepCnt) {
  __shared__ int snP;
  __shared__ float wsum[BLOCK / 64], wcnt[BLOCK / 64];
  if (threadIdx.x == 0) snP = (int)atomicAdd(pendCnt, 0u);
  __syncthreads();
  const int lane = threadIdx.x & 63, wid = threadIdx.x >> 6;
  const int gw = blockIdx.x * (BLOCK / 64) + wid;
  const int nW = PBLOCKS * (BLOCK / 64);
  float v = 0.f, c = 0.f;

  for (int it = gw; it < snP; it += nW) {
    const unsigned qi = wl[it];
    const float4 p = q[qi];
    const int cx = cellOf3(p.x), cy = cellOf3(p.y), cz = cellOf3(p.z);
    float best = wlBest[it];   // wave-uniform (same address)

    for (int r = 1; r <= 2; ++r) {
      const float cov = H3 * (float)(r - 1);
      if (best <= cov * cov) break;             // exact already
      const int S = (r == 1) ? 9 : 34;          // ring1: 3x3x3 rows; ring2 shell
      float b = best;
      for (int sI = lane; sI < S; sI += 64) {
        int dz, dy, xa, xb;
        if (r == 1) {                           // full 3x3x3 medium rows
          dz = sI / 3 - 1; dy = sI % 3 - 1; xa = cx - 1; xb = cx + 1;
        } else if (sI < 16) {                   // shell faces: full x rows
          if (sI < 5)       { dz = -2; dy = sI - 2; }
          else if (sI < 10) { dz =  2; dy = sI - 5 - 2; }
          else { const int t2 = sI - 10; dz = (t2 >> 1) - 1;
                 dy = (t2 & 1) ? 2 : -2; }
          xa = cx - 2; xb = cx + 2;
        } else {                                // interior rows: x = +/- 2 ends
          const int t2 = sI - 16, ci = t2 >> 1;
          dz = ci / 3 - 1; dy = ci % 3 - 1;
          xa = xb = (t2 & 1) ? cx + 2 : cx - 2;
        }
        const int Z = cz + dz, Y = cy + dy;
        if (Z < 0 || Z >= G3 || Y < 0 || Y >= G3) continue;
        const int a3 = max(xa, 0), e3 = min(xb, G3 - 1);
        if (a3 > e3) continue;
        const int xs = 2 * a3, xe = 2 * e3 + 1; // fine x-span
        unsigned js[4], je[4];
#pragma unroll
        for (int k = 0; k < 4; ++k) {
          const int zz = 2 * Z + (k >> 1), yy = 2 * Y + (k & 1);
          const int rb = (zz * G + yy) * G;
          js[k] = (rb + xs) ? ends[rb + xs - 1] : 0u;
          je[k] = ends[rb + xe];
        }
#pragma unroll
        for (int k = 0; k < 4; ++k) {
#pragma unroll 4
          for (unsigned j = js[k]; j < je[k]; ++j) {
            const float4 cd = s[j];
            const float dx = p.x - cd.x, dyv = p.y - cd.y, dzv = p.z - cd.z;
            b = fminf(b, fmaf(dx, dx, fmaf(dyv, dyv, dzv * dzv)));
          }
        }
      }
      for (int o = 32; o; o >>= 1) b = fminf(b, __shfl_xor(b, o, 64));
      best = b;                                 // wave-uniform again
    }

    if (lane == 0) {
      if (best > 0.25f) {                       // unsearched could hold the NN
        wl2[atomicAdd(deepCnt, 1u)] = qi;
      } else if (best <= 2.0f) { v += best; c += 1.0f; }
    }
  }

  if (lane == 0) { wsum[wid] = v; wcnt[wid] = c; }
  __syncthreads();
  if (threadIdx.x == 0) {
    float bv = 0.f, bc = 0.f;
    for (int w = 0; w < BLOCK / 64; ++w) { bv += wsum[w]; bc += wcnt[w]; }
    if (bc != 0.f) {
      atomicAdd(&bkt[2 * (blockIdx.x & 63) + 0], bv);
      atomicAdd(&bkt[2 * (blockIdx.x & 63) + 1], bc);
    }
  }
}

// Phase 3: block-per-query brute force over all of s (1MB). unroll-16 keeps
// 16 loads in flight per lane (R23's unroll-4 was latency-bound: 64x900cyc).
// Last block reduces the buckets and writes out.
__global__ __launch_bounds__(BLOCK) void deep_kernel(
    const float4* __restrict__ q, const float4* __restrict__ s,
    const unsigned* __restrict__ wl2, unsigned* __restrict__ deepCnt,
    float* __restrict__ bkt, unsigned* __restrict__ done,
    float* __restrict__ out) {
  __shared__ int snD;
  __shared__ float wmin[BLOCK / 64];
  __shared__ int isLast;
  __shared__ float fs[BLOCK / 64], fc[BLOCK / 64];
  if (threadIdx.x == 0) snD = (int)atomicAdd(deepCnt, 0u);
  __syncthreads();
  const int lane = threadIdx.x & 63, wid = threadIdx.x >> 6;
  float v = 0.f, c = 0.f;

  for (int it = blockIdx.x; it < snD; it += DBLOCKS) {
    const float4 p = q[wl2[it]];
    float best = 3.4e38f;
#pragma unroll 16
    for (int j = threadIdx.x; j < NPTS; j += BLOCK) {   // coalesced stream
      const float4 cd = s[j];
      const float dx = p.x - cd.x, dy = p.y - cd.y, dz = p.z - cd.z;
      best = fminf(best, fmaf(dx, dx, fmaf(dy, dy, dz * dz)));
    }
    for (int o = 32; o; o >>= 1) best = fminf(best, __shfl_xor(best, o, 64));
    if (lane == 0) wmin[wid] = best;
    __syncthreads();
    if (threadIdx.x == 0) {
      float b = wmin[0];
      for (int w = 1; w < BLOCK / 64; ++w) b = fminf(b, wmin[w]);
      if (b <= 2.0f) { v += b; c += 1.0f; }
    }
    __syncthreads();
  }

  if (threadIdx.x == 0) {
    if (c != 0.f) {
      atomicAdd(&bkt[2 * (blockIdx.x & 63) + 0], v);
      atomicAdd(&bkt[2 * (blockIdx.x & 63) + 1], c);
    }
    __threadfence();
    isLast = (atomicAdd(done, 1u) == (unsigned)(DBLOCKS - 1));
  }
  __syncthreads();
  if (isLast) {   // parallel coherent read of the 128 bucket slots + reduce
    const float val = (threadIdx.x < 128) ? atomicAdd(&bkt[threadIdx.x], 0.0f) : 0.0f;
    float sv = (threadIdx.x & 1) ? 0.f : val;
    float cv = (threadIdx.x & 1) ? val : 0.f;
    for (int o = 32; o; o >>= 1) {
      sv += __shfl_down(sv, o, 64);
      cv += __shfl_down(cv, o, 64);
    }
    if (lane == 0) { fs[wid] = sv; fc[wid] = cv; }
    __syncthreads();
    if (threadIdx.x == 0) {
      float S = 0.f, C = 0.f;
      for (int w = 0; w < BLOCK / 64; ++w) { S += fs[w]; C += fc[w]; }
      out[0] = S / C;
    }
  }
}

extern "C" void kernel_launch(void* const* d_in, const int* in_sizes, int n_in,
                              void* d_out, int out_size, void* d_ws, size_t ws_size,
                              hipStream_t stream) {
  const float* pc0 = (const float*)d_in[0];
  const float* pc1 = (const float*)d_in[1];
  float* out = (float*)d_out;

  // slab carve-up; counts1|counts0|misc contiguous -> single memset
  char* w = (char*)d_ws;
  auto nxt = [&](size_t bytes) {
    char* p = w; w += (bytes + 255) & ~(size_t)255; return p;
  };
  unsigned* counts1  = (unsigned*)nxt((size_t)NC * 4);           // 1 MB
  unsigned* counts0  = (unsigned*)nxt((size_t)NC * 4);           // 1 MB
  char*     misc     = nxt(1024);   // bkt[128] | done | pendCnt | deepCnt
  float*    bkt      = (float*)misc;
  unsigned* done     = (unsigned*)(misc + 512);
  unsigned* pendCnt  = (unsigned*)(misc + 516);
  unsigned* deepCnt  = (unsigned*)(misc + 520);
  unsigned* partials = (unsigned*)nxt((size_t)2 * SB * 4);       // 1 KB
  unsigned* cur1     = (unsigned*)nxt((size_t)NC * 4);           // 1 MB
  unsigned* cur0     = (unsigned*)nxt((size_t)NC * 4);           // 1 MB
  float4*   s        = (float4*)nxt((size_t)NPTS * 16);          // 1 MB
  float4*   q        = (float4*)nxt((size_t)NPTS * 16);          // 1 MB
  unsigned* wl       = (unsigned*)nxt((size_t)NPTS * 4);         // 256 KB
  float*    wlBest   = (float*)nxt((size_t)NPTS * 4);            // 256 KB
  unsigned* wl2      = (unsigned*)nxt((size_t)NPTS * 4);         // 256 KB

  hipMemsetAsync(counts1, 0, (size_t)2 * NC * 4 + 1024, stream);

  count_kernel<<<2 * NPTS / BLOCK, BLOCK, 0, stream>>>(pc0, pc1, counts0, counts1);
  scan_partial_kernel<<<dim3(SB, 2), 1024, 0, stream>>>(counts0, counts1, partials);
  scan_mid_kernel<<<1, 256, 0, stream>>>(partials);
  scan_final_kernel<<<dim3(SB, 2), 1024, 0, stream>>>(counts0, cur0,
                                                      counts1, cur1, partials);
  scatter_kernel<<<2 * NPTS / BLOCK, BLOCK, 0, stream>>>(
      pc0, pc1, cur0, cur1, q, s);
  query_kernel<<<2 * NPTS / BLOCK, BLOCK, 0, stream>>>(q, cur1, s, wl, wlBest,
                                                       pendCnt, bkt);
  pending_kernel<<<PBLOCKS, BLOCK, 0, stream>>>(q, cur1, s, wl, wlBest,
                                                pendCnt, bkt, wl2, deepCnt);
  deep_kernel<<<DBLOCKS, BLOCK, 0, stream>>>(q, s, wl2, deepCnt, bkt, done, out);
}

// Round 25
// 151.270 us; speedup vs baseline: 1.5704x; 1.5704x over previous
//
#include <hip/hip_runtime.h>

// Chamfer forward: dist0[i] = min_j ||pc0[i]-pc1[j]||^2 ; out = mean(dist0[dist0<=2])
// N = M = 65536 i.i.d. N(0,1)^3 points, fp32.
// REVERT to R22 (measured best: 148.2us). R23/R24's brute-force tail regressed
// (60/128us: L2 contention - all deep blocks streaming the same 1MB array).
// Fine grid G=64 (h=0.125), counting sort, two-phase query:
//   query: fine rings 0..1, 2 lanes/query; pending: wave/query, medium ring
//   geometry (G3=32) emulated over the fine CSR (4 fine rows per medium row).
// Plateau evidence: R16/R17/R18/R20/R21/R22 = 154/153/157/151/150/148us across
// different work splits; harness ws-poison fill = 41us @ 81% HBM (its roofline);
// algorithmic work ~4e7 pairs << 1us VALU - pipeline is latency+overhead-bound.

constexpr int   NPTS  = 65536;
constexpr int   G     = 64;
constexpr int   NC    = G * G * G;    // 262144 fine cells
constexpr float H     = 0.125f;
constexpr float ORG   = -4.0f;
constexpr float INVH  = 8.0f;
constexpr int   G3    = 32;           // medium geometry (phase 2 rings)
constexpr float H3    = 0.25f;
constexpr float INVH3 = 4.0f;
constexpr int   BLOCK = 256;
constexpr int   PBLOCKS = 1024;       // pending grid: 4096 waves >= pending count
constexpr int   SB    = 128;          // scan blocks per fine array
constexpr int   CHUNK = NC / SB;      // 2048 counts per scan block (2/thread)

__device__ __forceinline__ int cellOf(float x) {
  int c = (int)floorf((x - ORG) * INVH);
  return min(max(c, 0), G - 1);
}
__device__ __forceinline__ int cellOf3(float x) {
  int c = (int)floorf((x - ORG) * INVH3);
  return min(max(c, 0), G3 - 1);
}

__global__ __launch_bounds__(BLOCK) void count_kernel(
    const float* __restrict__ pc0, const float* __restrict__ pc1,
    unsigned* __restrict__ counts0, unsigned* __restrict__ counts1) {
  const int gid = blockIdx.x * BLOCK + threadIdx.x;
  const float* p; unsigned* cnt; int i;
  if (gid < NPTS) { p = pc1; cnt = counts1; i = gid; }
  else            { p = pc0; cnt = counts0; i = gid - NPTS; }
  const float x = p[3 * i], y = p[3 * i + 1], z = p[3 * i + 2];
  atomicAdd(&cnt[(cellOf(z) * G + cellOf(y)) * G + cellOf(x)], 1u);
}

// Phase A: per-block partial sums. grid=(SB,2); y=0->counts1, y=1->counts0.
__global__ __launch_bounds__(1024) void scan_partial_kernel(
    const unsigned* __restrict__ counts0, const unsigned* __restrict__ counts1,
    unsigned* __restrict__ partials) {
  const unsigned* counts = blockIdx.y ? counts0 : counts1;
  const int base = blockIdx.x * CHUNK + threadIdx.x * 2;
  unsigned sum = counts[base] + counts[base + 1];
  for (int o = 32; o; o >>= 1) sum += __shfl_down(sum, o, 64);
  __shared__ unsigned ws[16];
  if ((threadIdx.x & 63) == 0) ws[threadIdx.x >> 6] = sum;
  __syncthreads();
  if (threadIdx.x == 0) {
    unsigned t = 0;
    for (int w = 0; w < 16; ++w) t += ws[w];
    partials[blockIdx.y * SB + blockIdx.x] = t;
  }
}

// Phase B: one 256-thread block exclusively scans both 128-entry partial arrays.
__global__ __launch_bounds__(256) void scan_mid_kernel(
    unsigned* __restrict__ partials) {
  const int tid = threadIdx.x;
  const int g   = tid >> 7;
  const int li  = tid & 127;
  const unsigned v = partials[g * SB + li];
  unsigned inc = v;
  for (int o = 1; o < 64; o <<= 1) {
    const unsigned t = __shfl_up(inc, o, 64);
    if ((tid & 63) >= o) inc += t;
  }
  __shared__ unsigned wt[4];
  if ((tid & 63) == 63) wt[tid >> 6] = inc;
  __syncthreads();
  const unsigned woff = ((tid >> 6) & 1) ? wt[g << 1] : 0u;
  partials[g * SB + li] = woff + inc - v;
}

// Phase C: block scan + offset -> cur (CSR starts). grid=(SB,2).
__global__ __launch_bounds__(1024) void scan_final_kernel(
    const unsigned* __restrict__ counts0, unsigned* __restrict__ cur0,
    const unsigned* __restrict__ counts1, unsigned* __restrict__ cur1,
    const unsigned* __restrict__ partials) {
  const unsigned* counts = blockIdx.y ? counts0 : counts1;
  unsigned* cur          = blockIdx.y ? cur0    : cur1;
  const int tid = threadIdx.x;
  const int base = blockIdx.x * CHUNK + tid * 2;
  const unsigned a = counts[base], b = counts[base + 1];
  const unsigned tsum = a + b;
  unsigned inc = tsum;
  for (int o = 1; o < 64; o <<= 1) {
    const unsigned t = __shfl_up(inc, o, 64);
    if ((tid & 63) >= o) inc += t;
  }
  __shared__ unsigned wt[16];
  if ((tid & 63) == 63) wt[tid >> 6] = inc;
  __syncthreads();
  if (tid < 16) {
    unsigned w = wt[tid];
    for (int o = 1; o < 16; o <<= 1) {
      const unsigned t = __shfl_up(w, o, 16);
      if (tid >= o) w += t;
    }
    wt[tid] = w;
  }
  __syncthreads();
  const unsigned woff = (tid >> 6) ? wt[(tid >> 6) - 1] : 0u;
  const unsigned off =
      partials[blockIdx.y * SB + blockIdx.x] + woff + inc - tsum;
  cur[base] = off;
  cur[base + 1] = off + a;
}

// After scatter, cur[c] = CSR inclusive end of cell c (start = cur[c-1]).
__global__ __launch_bounds__(BLOCK) void scatter_kernel(
    const float* __restrict__ pc0, const float* __restrict__ pc1,
    unsigned* __restrict__ cur0, unsigned* __restrict__ cur1,
    float4* __restrict__ q, float4* __restrict__ s) {
  const int gid = blockIdx.x * BLOCK + threadIdx.x;
  const float* p; unsigned* cur; float4* dst; int i;
  if (gid < NPTS) { p = pc1; cur = cur1; dst = s; i = gid; }
  else            { p = pc0; cur = cur0; dst = q; i = gid - NPTS; }
  const float x = p[3 * i], y = p[3 * i + 1], z = p[3 * i + 2];
  const int cid = (cellOf(z) * G + cellOf(y)) * G + cellOf(x);
  dst[atomicAdd(&cur[cid], 1u)] = make_float4(x, y, z, 0.f);
}

// Phase 1: fine rings 0..1, 2 lanes per query; push unfinished to worklist.
__global__ __launch_bounds__(BLOCK) void query_kernel(
    const float4* __restrict__ q, const unsigned* __restrict__ ends,
    const float4* __restrict__ s,
    unsigned* __restrict__ wl, float* __restrict__ wlBest,
    unsigned* __restrict__ pendCnt, float* __restrict__ bkt) {
  const int gtid = blockIdx.x * BLOCK + threadIdx.x;
  const int i   = gtid >> 1;        // query index
  const int sub = gtid & 1;         // sub-lane
  const float4 p = q[i];
  const int cx = cellOf(p.x), cy = cellOf(p.y), cz = cellOf(p.z);
  const int x0 = max(cx - 1, 0), x1 = min(cx + 1, G - 1);

  unsigned rs[9], re[9];
#pragma unroll
  for (int rr = 0; rr < 9; ++rr) {
    const int zz = cz + rr / 3 - 1, yy = cy + rr % 3 - 1;
    const bool ok = (zz >= 0) && (zz < G) && (yy >= 0) && (yy < G);
    const int rb = ok ? (zz * G + yy) * G : 0;
    rs[rr] = ok ? ((rb + x0) ? ends[rb + x0 - 1] : 0u) : 0u;
    re[rr] = ok ? ends[rb + x1] : 0u;
  }
  float best = 3.4e38f;
#pragma unroll
  for (int rr = 0; rr < 9; ++rr) {
#pragma unroll 4
    for (unsigned j = rs[rr] + sub; j < re[rr]; j += 2) {
      const float4 c = s[j];
      const float dx = p.x - c.x, dy = p.y - c.y, dz = p.z - c.z;
      best = fminf(best, fmaf(dx, dx, fmaf(dy, dy, dz * dz)));
    }
  }
  best = fminf(best, __shfl_xor(best, 1, 64));   // combine the 2 sub-lanes

  float v = 0.f, c = 0.f;
  if (sub == 0) {
    if (best > H * H) {            // not provably exact -> phase 2
      const unsigned k = atomicAdd(pendCnt, 1u);
      wl[k] = (unsigned)i; wlBest[k] = best;
    } else if (best <= 2.0f) { v = best; c = 1.0f; }
  }

  for (int o = 32; o; o >>= 1) {
    v += __shfl_down(v, o, 64);
    c += __shfl_down(c, o, 64);
  }
  __shared__ float wsum[BLOCK / 64], wcnt[BLOCK / 64];
  const int wid = threadIdx.x >> 6;
  if ((threadIdx.x & 63) == 0) { wsum[wid] = v; wcnt[wid] = c; }
  __syncthreads();
  if (threadIdx.x == 0) {
    float bv = 0.f, bc = 0.f;
    for (int w = 0; w < BLOCK / 64; ++w) { bv += wsum[w]; bc += wcnt[w]; }
    if (bc != 0.f) {
      atomicAdd(&bkt[2 * (blockIdx.x & 63) + 0], bv);
      atomicAdd(&bkt[2 * (blockIdx.x & 63) + 1], bc);
    }
  }
}

// Phase 2: one wave per pending query; MEDIUM ring geometry over the FINE CSR
// (one medium row = 4 fine rows). Ring 1 = full 3x3x3 medium; r=8 head always
// terminates. Candidate loop unroll-4: 4 loads in flight per lane.
__global__ __launch_bounds__(BLOCK) void pending_kernel(
    const float4* __restrict__ q,
    const unsigned* __restrict__ ends, const float4* __restrict__ s,
    const unsigned* __restrict__ wl, const float* __restrict__ wlBest,
    unsigned* __restrict__ pendCnt, float* __restrict__ bkt,
    unsigned* __restrict__ done, float* __restrict__ out) {
  __shared__ int snP;
  __shared__ float wsum[BLOCK / 64], wcnt[BLOCK / 64];
  __shared__ int isLast;
  __shared__ float fs[BLOCK / 64], fc[BLOCK / 64];
  if (threadIdx.x == 0) snP = (int)atomicAdd(pendCnt, 0u);
  __syncthreads();
  const int lane = threadIdx.x & 63, wid = threadIdx.x >> 6;
  const int gw = blockIdx.x * (BLOCK / 64) + wid;
  const int nW = PBLOCKS * (BLOCK / 64);
  float v = 0.f, c = 0.f;

  for (int it = gw; it < snP; it += nW) {
    const unsigned qi = wl[it];
    const float4 p = q[qi];
    const int cx = cellOf3(p.x), cy = cellOf3(p.y), cz = cellOf3(p.z);
    float best = wlBest[it];   // wave-uniform (same address)

    for (int r = 1; r <= 8; ++r) {
      const float cov = H3 * (float)(r - 1);    // unscanned dist lower bound
      if (best <= cov * cov) break;             // exact
      if (best > 2.0f && cov * cov >= 2.0f) break;  // masked out either way
      const int S = (r == 1) ? 9 : 8 * r + 2 * (2 * r - 1) * (2 * r - 1);
      float b = best;
      for (int sI = lane; sI < S; sI += 64) {
        int dz, dy, xa, xb;
        if (r == 1) {                           // full 3x3x3 medium rows
          dz = sI / 3 - 1; dy = sI % 3 - 1; xa = cx - 1; xb = cx + 1;
        } else if (sI < 8 * r) {                // shell faces: full x rows
          if (sI < 2 * r + 1)      { dz = -r; dy = sI - r; }
          else if (sI < 4 * r + 2) { dz =  r; dy = sI - (2 * r + 1) - r; }
          else { const int t2 = sI - (4 * r + 2); dz = (t2 >> 1) - (r - 1);
                 dy = (t2 & 1) ? r : -r; }
          xa = cx - r; xb = cx + r;
        } else {                                // interior rows: x = +/- r ends
          const int t2 = sI - 8 * r, ci = t2 >> 1, w1 = 2 * r - 1;
          dz = ci / w1 - (r - 1); dy = ci % w1 - (r - 1);
          xa = xb = (t2 & 1) ? cx + r : cx - r;
        }
        const int Z = cz + dz, Y = cy + dy;
        if (Z < 0 || Z >= G3 || Y < 0 || Y >= G3) continue;
        const int a3 = max(xa, 0), e3 = min(xb, G3 - 1);
        if (a3 > e3) continue;
        const int xs = 2 * a3, xe = 2 * e3 + 1; // fine x-span
        // 4 fine rows per medium row; ranges preloaded (independent loads)
        unsigned js[4], je[4];
#pragma unroll
        for (int k = 0; k < 4; ++k) {
          const int zz = 2 * Z + (k >> 1), yy = 2 * Y + (k & 1);
          const int rb = (zz * G + yy) * G;
          js[k] = (rb + xs) ? ends[rb + xs - 1] : 0u;
          je[k] = ends[rb + xe];
        }
#pragma unroll
        for (int k = 0; k < 4; ++k) {
#pragma unroll 4
          for (unsigned j = js[k]; j < je[k]; ++j) {
            const float4 cd = s[j];
            const float dx = p.x - cd.x, dyv = p.y - cd.y, dzv = p.z - cd.z;
            b = fminf(b, fmaf(dx, dx, fmaf(dyv, dyv, dzv * dzv)));
          }
        }
      }
      for (int o = 32; o; o >>= 1) b = fminf(b, __shfl_xor(b, o, 64));
      best = b;                                 // wave-uniform again
    }
    if (lane == 0 && best <= 2.0f) { v += best; c += 1.0f; }
  }

  if (lane == 0) { wsum[wid] = v; wcnt[wid] = c; }
  __syncthreads();
  if (threadIdx.x == 0) {
    float bv = 0.f, bc = 0.f;
    for (int w = 0; w < BLOCK / 64; ++w) { bv += wsum[w]; bc += wcnt[w]; }
    if (bc != 0.f) {
      atomicAdd(&bkt[2 * (blockIdx.x & 63) + 0], bv);
      atomicAdd(&bkt[2 * (blockIdx.x & 63) + 1], bc);
    }
    __threadfence();
    isLast = (atomicAdd(done, 1u) == (unsigned)(PBLOCKS - 1));
  }
  __syncthreads();
  if (isLast) {   // parallel coherent read of the 128 bucket slots + reduce
    const float val = (threadIdx.x < 128) ? atomicAdd(&bkt[threadIdx.x], 0.0f) : 0.0f;
    float sv = (threadIdx.x & 1) ? 0.f : val;
    float cv = (threadIdx.x & 1) ? val : 0.f;
    for (int o = 32; o; o >>= 1) {
      sv += __shfl_down(sv, o, 64);
      cv += __shfl_down(cv, o, 64);
    }
    if (lane == 0) { fs[wid] = sv; fc[wid] = cv; }
    __syncthreads();
    if (threadIdx.x == 0) {
      float S = 0.f, C = 0.f;
      for (int w = 0; w < BLOCK / 64; ++w) { S += fs[w]; C += fc[w]; }
      out[0] = S / C;
    }
  }
}

extern "C" void kernel_launch(void* const* d_in, const int* in_sizes, int n_in,
                              void* d_out, int out_size, void* d_ws, size_t ws_size,
                              hipStream_t stream) {
  const float* pc0 = (const float*)d_in[0];
  const float* pc1 = (const float*)d_in[1];
  float* out = (float*)d_out;

  // slab carve-up; counts1|counts0|misc contiguous -> single memset
  char* w = (char*)d_ws;
  auto nxt = [&](size_t bytes) {
    char* p = w; w += (bytes + 255) & ~(size_t)255; return p;
  };
  unsigned* counts1  = (unsigned*)nxt((size_t)NC * 4);           // 1 MB
  unsigned* counts0  = (unsigned*)nxt((size_t)NC * 4);           // 1 MB
  char*     misc     = nxt(1024);   // bkt[128] | done | pendCnt
  float*    bkt      = (float*)misc;
  unsigned* done     = (unsigned*)(misc + 512);
  unsigned* pendCnt  = (unsigned*)(misc + 516);
  unsigned* partials = (unsigned*)nxt((size_t)2 * SB * 4);       // 1 KB
  unsigned* cur1     = (unsigned*)nxt((size_t)NC * 4);           // 1 MB
  unsigned* cur0     = (unsigned*)nxt((size_t)NC * 4);           // 1 MB
  float4*   s        = (float4*)nxt((size_t)NPTS * 16);          // 1 MB
  float4*   q        = (float4*)nxt((size_t)NPTS * 16);          // 1 MB
  unsigned* wl       = (unsigned*)nxt((size_t)NPTS * 4);         // 256 KB
  float*    wlBest   = (float*)nxt((size_t)NPTS * 4);            // 256 KB

  hipMemsetAsync(counts1, 0, (size_t)2 * NC * 4 + 1024, stream);

  count_kernel<<<2 * NPTS / BLOCK, BLOCK, 0, stream>>>(pc0, pc1, counts0, counts1);
  scan_partial_kernel<<<dim3(SB, 2), 1024, 0, stream>>>(counts0, counts1, partials);
  scan_mid_kernel<<<1, 256, 0, stream>>>(partials);
  scan_final_kernel<<<dim3(SB, 2), 1024, 0, stream>>>(counts0, cur0,
                                                      counts1, cur1, partials);
  scatter_kernel<<<2 * NPTS / BLOCK, BLOCK, 0, stream>>>(
      pc0, pc1, cur0, cur1, q, s);
  query_kernel<<<2 * NPTS / BLOCK, BLOCK, 0, stream>>>(q, cur1, s, wl, wlBest,
                                                       pendCnt, bkt);
  pending_kernel<<<PBLOCKS, BLOCK, 0, stream>>>(q, cur1, s, wl, wlBest,
                                                pendCnt, bkt, done, out);
}